// Round 7
// baseline (328.857 us; speedup 1.0000x reference)
//
#include <hip/hip_runtime.h>
#include <hip/hip_bf16.h>
#include <math.h>

#define TT 2048
#define NB 16

typedef short short8 __attribute__((ext_vector_type(8)));   // 8 bf16 (4 VGPR) MFMA frag
typedef float f32x4 __attribute__((ext_vector_type(4)));
typedef unsigned short us4 __attribute__((ext_vector_type(4)));

#define MFMA16(a,b,c) __builtin_amdgcn_mfma_f32_16x16x32_bf16((a),(b),(c),0,0,0)

typedef const __attribute__((address_space(1))) unsigned gas_u32;
typedef __attribute__((address_space(3))) unsigned las_u32;

__device__ __forceinline__ void gll16(const void* g, void* l) {
    // global->LDS direct copy, 16B per lane; dest = wave-uniform base + lane*16
    __builtin_amdgcn_global_load_lds((gas_u32*)g, (las_u32*)l, 16, 0, 0);
}

__device__ __forceinline__ unsigned short bf16rn(float f) {
    unsigned u = __float_as_uint(f);
    u += 0x7FFFu + ((u >> 16) & 1u);        // round-to-nearest-even
    return (unsigned short)(u >> 16);
}
__device__ __forceinline__ float bf16tof(unsigned short h) {
    return __uint_as_float(((unsigned)h) << 16);
}

// strip i (32 t-rows): number of preceding strip-tiles = h*(h+1) + (i&1)*(h+1), h=i>>1
__device__ __forceinline__ int strip_base(int i) {
    int h = i >> 1;
    return h * (h + 1) + (i & 1) * (h + 1);
}

// ---------------------------------------------------------------------------
// Kernel 0: W prep.  W[k][n] fp32 -> WT[m][part][n][1024 k] bf16 hi/lo.
// Wq additionally scaled by log2(e) so softmax uses exp2 directly.
// ---------------------------------------------------------------------------
__global__ void wprep_kernel(const float* __restrict__ Wq,
                             const float* __restrict__ Wk,
                             const float* __restrict__ Wv,
                             short* __restrict__ WT)
{
    const int m = blockIdx.x >> 6, n = blockIdx.x & 63, tid = threadIdx.x;
    const float* W = (m == 0) ? Wq : ((m == 1) ? Wk : Wv);
    const float sc = (m == 0) ? 1.4426950408889634f : 1.f;
    const int k0 = tid * 4;
    us4 hv, lv;
#pragma unroll
    for (int r = 0; r < 4; ++r) {
        float v = W[(size_t)(k0 + r) * 64 + n] * sc;
        unsigned short hh = bf16rn(v);
        hv[r] = hh;
        lv[r] = bf16rn(v - bf16tof(hh));
    }
    *(us4*)&WT[((size_t)(m * 2 + 0) * 64 + n) * 1024 + k0] = hv;
    *(us4*)&WT[((size_t)(m * 2 + 1) * 64 + n) * 1024 + k0] = lv;
}

// ---------------------------------------------------------------------------
// zero dcol (ws is re-poisoned to 0xAA before every timed launch)
// ---------------------------------------------------------------------------
__global__ void zero_kernel(float* __restrict__ p) {
    p[blockIdx.x * 256 + threadIdx.x] = 0.f;
}

// ---------------------------------------------------------------------------
// Kernel 1: QKV.  64 rows/block, 4 waves of 16 rows, grid 512.
// Pipelined: dbuf W (2x48 KB) + dbuf raw-f32 x (2x16 KB, XOR-swizzled units);
// per kc: issue 16 gll16 for kc+1, vmcnt(16), barrier, compute, barrier.
// x hi/lo bf16 conversion happens on LDS read (in compute phase).
// q,k SWAPPED (D[n][t] = Wt x^T) -> qhl/khl[b][t][part][64] hi/lo.
// v normal (D[t][d]), single hi pass -> vT[b][d][t] bf16.
// ---------------------------------------------------------------------------
__global__ __launch_bounds__(256, 1) void qkv_kernel(
    const float* __restrict__ x,
    const float* __restrict__ bq, const float* __restrict__ bk,
    const float* __restrict__ bv,
    const short* __restrict__ WT,
    short* __restrict__ qhl, short* __restrict__ khl, short* __restrict__ vT)
{
    __shared__ short ws[2][24576];    // [buf][part 2][kk 2][n 192][g8 4][8]
    __shared__ float xsf[2][2][64][32]; // [buf][kk 2][row 64][32 f32] (units swizzled)
    const int tid = threadIdx.x;
    const int w = tid >> 6, l15 = tid & 15, g = (tid >> 4) & 3;
    const int t0 = blockIdx.x * 64;
    const int u0x = (2 * g) ^ (l15 & 7);        // xsf swizzled unit indices
    const int u1x = (2 * g + 1) ^ (l15 & 7);

    f32x4 acc[12];
    const f32x4 z = {0.f, 0.f, 0.f, 0.f};
#pragma unroll
    for (int i = 0; i < 12; ++i) acc[i] = z;

    // stage W chunk kc into ws[buf]: 12 gll16/thread (3072 16B units)
    auto stageW = [&](int kc, int buf) {
#pragma unroll
        for (int p = 0; p < 12; ++p) {
            int u = tid + p * 256;
            int part = u / 1536; int r = u - part * 1536;
            int kk = r / 768;    int r2 = r - kk * 768;
            int n = r2 >> 2, g8 = r2 & 3;
            int m = n >> 6, nn = n & 63;
            const short* src = WT + (((size_t)((m * 2 + part) * 64 + nn)) << 10)
                                  + kc * 64 + kk * 32 + g8 * 8;
            gll16(src, &ws[buf][((tid & ~63) + p * 256) * 8]);
        }
    };
    // stage x chunk kc into xsf[buf]: 4 gll16/thread (1024 16B units, swizzled src)
    auto stageX = [&](int kc, int buf) {
#pragma unroll
        for (int p = 0; p < 4; ++p) {
            int u = tid + p * 256;
            int kk = u >> 9, rem = u & 511;
            int row = rem >> 3, ul = rem & 7;
            int uu = ul ^ (row & 7);            // involution swizzle
            gll16(x + (size_t)(t0 + row) * 1024 + kc * 64 + kk * 32 + uu * 4,
                  &xsf[buf][0][0][0] + ((tid & ~63) + p * 256) * 4);
        }
    };

    stageX(0, 0);
    stageW(0, 0);
#pragma unroll 1
    for (int kc = 0; kc < 16; ++kc) {
        const int buf = kc & 1;
        if (kc < 15) {
            stageX(kc + 1, buf ^ 1);
            stageW(kc + 1, buf ^ 1);
            asm volatile("s_waitcnt vmcnt(16)" ::: "memory");
        } else {
            asm volatile("s_waitcnt vmcnt(0)" ::: "memory");
        }
        __builtin_amdgcn_s_barrier();

#pragma unroll
        for (int kk = 0; kk < 2; ++kk) {
            f32x4 lo4 = *(const f32x4*)&xsf[buf][kk][w * 16 + l15][u0x * 4];
            f32x4 hi4 = *(const f32x4*)&xsf[buf][kk][w * 16 + l15][u1x * 4];
            short8 xh, xl;
#pragma unroll
            for (int j = 0; j < 4; ++j) {
                unsigned short hh = bf16rn(lo4[j]);
                xh[j] = (short)hh; xl[j] = (short)bf16rn(lo4[j] - bf16tof(hh));
                hh = bf16rn(hi4[j]);
                xh[j + 4] = (short)hh; xl[j + 4] = (short)bf16rn(hi4[j] - bf16tof(hh));
            }
#pragma unroll
            for (int Nb = 0; Nb < 12; ++Nb) {
                short8 wh = *(const short8*)&ws[buf][((kk * 192 + Nb * 16 + l15) * 4 + g) * 8];
                if (Nb < 8) {    // q,k: swapped, 3-pass hi/lo
                    short8 wl = *(const short8*)
                        &ws[buf][(((2 + kk) * 192 + Nb * 16 + l15) * 4 + g) * 8];
                    acc[Nb] = MFMA16(wh, xh, acc[Nb]);
                    acc[Nb] = MFMA16(wh, xl, acc[Nb]);
                    acc[Nb] = MFMA16(wl, xh, acc[Nb]);
                } else {         // v: normal, single hi pass
                    acc[Nb] = MFMA16(xh, wh, acc[Nb]);
                }
            }
        }
        __builtin_amdgcn_s_barrier();
    }

    const float LOG2E = 1.4426950408889634f;
#pragma unroll
    for (int Nb = 0; Nb < 12; ++Nb) {
        f32x4 a = acc[Nb];
        if (Nb < 8) {
            // D[n][t]: n = Nb*16 + g*4 + r, t = t0 + w*16 + l15
            const bool isq = (Nb < 4);
            const int nbase = (Nb & 3) * 16 + g * 4;
            const int trow = t0 + w * 16 + l15;
            const float* bias = isq ? bq : bk;
            us4 hv, lv;
#pragma unroll
            for (int r = 0; r < 4; ++r) {
                float v = a[r] + (isq ? bias[nbase + r] * LOG2E : bias[nbase + r]);
                unsigned short hh = bf16rn(v);
                hv[r] = hh; lv[r] = bf16rn(v - bf16tof(hh));
            }
            short* dst = (isq ? qhl : khl) + ((size_t)trow * 2) * 64 + nbase;
            *(us4*)dst = hv;
            *(us4*)(dst + 64) = lv;
        } else {
            // D[t][d]: t = t0 + w*16 + g*4 + r, d = (Nb-8)*16 + l15
            const int d = (Nb - 8) * 16 + l15;
            const int tbase = t0 + w * 16 + g * 4;
            const float bvd = bv[d];
            us4 pk;
#pragma unroll
            for (int r = 0; r < 4; ++r) pk[r] = bf16rn(a[r] + bvd);
            const int b = tbase >> 11, ttl = tbase & 2047;
            *(us4*)&vT[((size_t)(b * 64 + d)) * 2048 + ttl] = pk;
        }
    }
}

// ---------------------------------------------------------------------------
// Kernel 2: column sums D[s] = sum_{t>=s} 2^{S'[t,s]} (fixed ref m=0) AND
// stores P = 2^{S'} bf16 in strip-tile MFMA-B-fragment layout.
// Pipelined: dbuf qb; per tile: issue q[tt+1] (4 gll16), vmcnt(8) [leaves
// next loads + P-stores in flight], barrier, compute+store, barrier.
// Grid (32 sblk, 4 tchunk, 16 b), partial D via fp32 atomicAdd.
// ---------------------------------------------------------------------------
__global__ __launch_bounds__(256, 3) void colstatsP_kernel(
    const short* __restrict__ qhl, const short* __restrict__ khl,
    float* __restrict__ dcol, short* __restrict__ Pst)
{
    __shared__ short kb[8192];      // [part 2][kk 2][row 64][g8][8]
    __shared__ short qb[2][8192];
    const int tid = threadIdx.x;
    const int w = tid >> 6, l15 = tid & 15, g = (tid >> 4) & 3;
    const int sblk = blockIdx.x, tc = blockIdx.y, b = blockIdx.z;
    const int tt0 = max(sblk, tc * 8), tt1 = min(32, tc * 8 + 8);
    if (tt0 >= tt1) return;
    const int s0 = sblk * 64;
    const int sl = w * 16 + g * 4;
    const int kgs = w >> 1, g8s = (w & 1) * 2 + (g >> 1), j0 = (g & 1) * 4;

    auto stageQ = [&](int tt, int buf) {
#pragma unroll
        for (int p = 0; p < 4; ++p) {
            int u = tid + p * 256;
            int part = u >> 9, kk = (u >> 8) & 1, row = (u >> 2) & 63, g8 = u & 3;
            gll16(qhl + ((size_t)(b * TT + tt * 64 + row) * 2 + part) * 64 + kk * 32 + g8 * 8,
                  &qb[buf][((tid & ~63) + p * 256) * 8]);
        }
    };

#pragma unroll
    for (int p = 0; p < 4; ++p) {
        int u = tid + p * 256;
        int part = u >> 9, kk = (u >> 8) & 1, row = (u >> 2) & 63, g8 = u & 3;
        gll16(khl + ((size_t)(b * TT + s0 + row) * 2 + part) * 64 + kk * 32 + g8 * 8,
              &kb[((tid & ~63) + p * 256) * 8]);
    }
    stageQ(tt0, 0);
    asm volatile("s_waitcnt vmcnt(0)" ::: "memory");
    __builtin_amdgcn_s_barrier();

    short8 kf[2][2];
#pragma unroll
    for (int kk = 0; kk < 2; ++kk)
#pragma unroll
        for (int part = 0; part < 2; ++part)
            kf[kk][part] = *(const short8*)
                &kb[(((part * 2 + kk) * 64 + w * 16 + l15) * 4 + g) * 8];

    float dsl[4] = {0.f, 0.f, 0.f, 0.f};
    const f32x4 z = {0.f, 0.f, 0.f, 0.f};
    int buf = 0;

#pragma unroll 1
    for (int tt = tt0; tt < tt1; ++tt) {
        if (tt + 1 < tt1) {
            stageQ(tt + 1, buf ^ 1);
            asm volatile("s_waitcnt vmcnt(8)" ::: "memory");
        } else {
            asm volatile("s_waitcnt vmcnt(4)" ::: "memory");
        }
        __builtin_amdgcn_s_barrier();

#pragma unroll
        for (int tb = 0; tb < 4; ++tb) {
            f32x4 a = z;
#pragma unroll
            for (int kk = 0; kk < 2; ++kk) {
                short8 qh = *(const short8*)&qb[buf][((kk * 64 + tb * 16 + l15) * 4 + g) * 8];
                short8 ql = *(const short8*)&qb[buf][(((2 + kk) * 64 + tb * 16 + l15) * 4 + g) * 8];
                a = MFMA16(kf[kk][0], qh, a);
                a = MFMA16(kf[kk][0], ql, a);
                a = MFMA16(kf[kk][1], qh, a);
            }
            if (tt == sblk) {   // diagonal tile: t_local < s_local -> masked
#pragma unroll
                for (int r = 0; r < 4; ++r)
                    if (tb * 16 + l15 < sl + r) a[r] = -INFINITY;
            }
            us4 pk;
#pragma unroll
            for (int r = 0; r < 4; ++r) {
                float p = exp2f(a[r]);     // exp2(-inf)=0 for masked
                dsl[r] += p;
                pk[r] = bf16rn(p);
            }
            const int strip = tt * 2 + (tb >> 1);
            const int t32 = (tb & 1) * 16 + l15;
            size_t toff = ((size_t)(b * 1056 + strip_base(strip) + sblk)) * 2048
                        + ((kgs * 32 + t32) * 4 + g8s) * 8 + j0;
            *(us4*)&Pst[toff] = pk;
        }
        __builtin_amdgcn_s_barrier();
        buf ^= 1;
    }
#pragma unroll
    for (int r = 0; r < 4; ++r) {
        float dv = dsl[r];
        dv += __shfl_xor(dv, 1); dv += __shfl_xor(dv, 2);
        dv += __shfl_xor(dv, 4); dv += __shfl_xor(dv, 8);
        dsl[r] = dv;
    }
    if (l15 == 0) {
#pragma unroll
        for (int r = 0; r < 4; ++r)
            atomicAdd(&dcol[(size_t)b * TT + s0 + sl + r], dsl[r]);
    }
}

// ---------------------------------------------------------------------------
// Kernel 2.5: v' = v / D  (normalization folded into V)
// ---------------------------------------------------------------------------
__global__ void vprep_kernel(const short* __restrict__ vT,
                             const float* __restrict__ dcol,
                             short* __restrict__ vT2)
{
    const int u = blockIdx.x * 256 + threadIdx.x;   // 262144 threads
    const int s8 = u & 255, bd = u >> 8;            // bd in [0,1024)
    const int b = bd >> 6;
    short8 v = *(const short8*)&vT[(size_t)bd * 2048 + s8 * 8];
    f32x4 d0 = *(const f32x4*)&dcol[(size_t)b * TT + s8 * 8];
    f32x4 d1 = *(const f32x4*)&dcol[(size_t)b * TT + s8 * 8 + 4];
    short8 o;
#pragma unroll
    for (int j = 0; j < 4; ++j) {
        o[j]     = (short)bf16rn(bf16tof((unsigned short)v[j])     / d0[j]);
        o[4 + j] = (short)bf16rn(bf16tof((unsigned short)v[4 + j]) / d1[j]);
    }
    *(short8*)&vT2[(size_t)bd * 2048 + s8 * 8] = o;
}

// ---------------------------------------------------------------------------
// Kernel 3: output = pure PV.  Block (p, b) owns strips iA=p, iB=63-p.
// 2-phase double-buffer with raw s_barrier + counted vmcnt(4).  (unchanged r6)
// ---------------------------------------------------------------------------
__global__ __launch_bounds__(256, 4) void attnout_kernel(
    const short* __restrict__ Pst, const short* __restrict__ vT2,
    float* __restrict__ out)
{
    __shared__ short vb[2][4096];    // [kgs 2][d 64][g8 4][8]
    __shared__ short ebA[2][2048];   // [kgs 2][t 32][g8 4][8]
    __shared__ short ebB[2][2048];
    const int tid = threadIdx.x;
    const int w = tid >> 6, l15 = tid & 15, g = (tid >> 4) & 3;
    const int p = blockIdx.x, b = blockIdx.y;
    const int iA = p, iB = 63 - p;
    const int nA = iA >> 1, nB = iB >> 1;
    const int sl = w * 16 + g * 4;

    const short* PA = Pst + ((size_t)(b * 1056 + strip_base(iA))) * 2048;
    const short* PB = Pst + ((size_t)(b * 1056 + strip_base(iB))) * 2048;
    const short* vbase = vT2 + (size_t)b * 64 * 2048;
    const int ldsu = (tid & ~63) * 8;   // wave-uniform LDS unit base (shorts)

    auto stage = [&](int ss, int buf) {
#pragma unroll
        for (int pp = 0; pp < 2; ++pp) {
            int u = tid + pp * 256;
            int kgs = u >> 8, d = (u >> 2) & 63, g8 = u & 3;
            gll16(vbase + ((size_t)d) * 2048 + ss * 64 + kgs * 32 + g8 * 8,
                  &vb[buf][ldsu + pp * 2048]);
        }
        gll16(PB + (size_t)ss * 2048 + tid * 8, &ebB[buf][ldsu]);
        gll16(PA + (size_t)ss * 2048 + tid * 8, &ebA[buf][ldsu]);  // garbage ok if ss>nA
    };

    f32x4 oaccA[2], oaccB[2];
    const f32x4 z = {0.f, 0.f, 0.f, 0.f};
    oaccA[0] = z; oaccA[1] = z; oaccB[0] = z; oaccB[1] = z;

    stage(0, 0);
#pragma unroll 1
    for (int ss = 0; ss <= nB; ++ss) {
        const int nss = (ss < nB) ? ss + 1 : nB;    // uniform 4-load stage every iter
        stage(nss, (ss + 1) & 1);
        asm volatile("s_waitcnt vmcnt(4)" ::: "memory");
        __builtin_amdgcn_s_barrier();
        asm volatile("" ::: "memory");

        const int cb_ = ss & 1;
        short8 vf[2];
#pragma unroll
        for (int kg = 0; kg < 2; ++kg)
            vf[kg] = *(const short8*)&vb[cb_][((kg * 64 + w * 16 + l15) * 4 + g) * 8];
#pragma unroll
        for (int tb = 0; tb < 2; ++tb)
#pragma unroll
            for (int kg = 0; kg < 2; ++kg) {
                short8 ef = *(const short8*)&ebB[cb_][((kg * 32 + tb * 16 + l15) * 4 + g) * 8];
                oaccB[tb] = MFMA16(vf[kg], ef, oaccB[tb]);
            }
        if (ss <= nA) {
#pragma unroll
            for (int tb = 0; tb < 2; ++tb)
#pragma unroll
                for (int kg = 0; kg < 2; ++kg) {
                    short8 ef = *(const short8*)&ebA[cb_][((kg * 32 + tb * 16 + l15) * 4 + g) * 8];
                    oaccA[tb] = MFMA16(vf[kg], ef, oaccA[tb]);
                }
        }
        asm volatile("" ::: "memory");
        __builtin_amdgcn_s_barrier();
    }

    // O^T D-frag: col = t (l15), row = d = w*16 + g*4 + r -> float4 along d
#pragma unroll
    for (int tb = 0; tb < 2; ++tb) {
        const int tA = iA * 32 + tb * 16 + l15;
        const int tB = iB * 32 + tb * 16 + l15;
        *(f32x4*)(out + ((size_t)(b * TT + tA)) * 64 + sl) = oaccA[tb];
        *(f32x4*)(out + ((size_t)(b * TT + tB)) * 64 + sl) = oaccB[tb];
    }
}

extern "C" void kernel_launch(void* const* d_in, const int* in_sizes, int n_in,
                              void* d_out, int out_size, void* d_ws, size_t ws_size,
                              hipStream_t stream)
{
    const float* x  = (const float*)d_in[0];
    const float* Wq = (const float*)d_in[1];
    const float* bq = (const float*)d_in[2];
    const float* Wk = (const float*)d_in[3];
    const float* bk = (const float*)d_in[4];
    const float* Wv = (const float*)d_in[5];
    const float* bv = (const float*)d_in[6];

    char* wsb = (char*)d_ws;
    short* qhl  = (short*)wsb;                       // 8,388,608 B
    short* khl  = (short*)(wsb + 8388608);           // 8,388,608 B
    short* vTb  = (short*)(wsb + 16777216);          // 4,194,304 B
    short* vT2  = (short*)(wsb + 20971520);          // 4,194,304 B
    short* WT   = (short*)(wsb + 25165824);          //   786,432 B
    float* dcol = (float*)(wsb + 25952256);          //   131,072 B
    short* Pst  = (short*)(wsb + 26083328);          // 69,206,016 B (total ~95.3 MB)

    zero_kernel<<<dim3(128), 256, 0, stream>>>(dcol);
    wprep_kernel<<<dim3(192), 256, 0, stream>>>(Wq, Wk, Wv, WT);
    qkv_kernel<<<dim3(512), 256, 0, stream>>>(x, bq, bk, bv, WT, qhl, khl, vTb);
    colstatsP_kernel<<<dim3(32, 4, NB), 256, 0, stream>>>(qhl, khl, dcol, Pst);
    vprep_kernel<<<dim3(1024), 256, 0, stream>>>(vTb, dcol, vT2);
    attnout_kernel<<<dim3(32, NB), 256, 0, stream>>>(Pst, vT2, (float*)d_out);
}